// Round 15
// baseline (113.210 us; speedup 1.0000x reference)
//
#include <hip/hip_runtime.h>
#include <math.h>

// Problem constants
#define NTOK 8192
#define DDIM 1024
#define NEXP 8
#define HDIM 256
#define TOPK 2
#define PADM 128                         // per-expert row padding
#define CAPS (NTOK * TOPK + NEXP * PADM) // 17408 slots max
#define NT32  (CAPS / 32)                // 544 row tiles (BM=32, egemm12)
#define NT128 (CAPS / 128)               // 136 row tiles (BM=128, egemm3)

typedef __attribute__((ext_vector_type(8))) __bf16 bf16x8;
typedef __attribute__((ext_vector_type(4))) float f32x4;

#define GLDS16(g, s)                                                      \
    __builtin_amdgcn_global_load_lds(                                     \
        (const __attribute__((address_space(1))) void*)(g),               \
        (__attribute__((address_space(3))) void*)(s), 16, 0, 0)

// counted-vmcnt pipeline primitives (T4): raw barrier, never drain in-loop
#define VMCNT9 asm volatile("s_waitcnt vmcnt(9)" ::: "memory")
#define VMCNT8 asm volatile("s_waitcnt vmcnt(8)" ::: "memory")
#define VMCNT0 asm volatile("s_waitcnt vmcnt(0)" ::: "memory")
#define LGKM0  asm volatile("s_waitcnt lgkmcnt(0)" ::: "memory")
#define SBAR() __builtin_amdgcn_s_barrier()
#define SCHED0() __builtin_amdgcn_sched_barrier(0)

// ---------------- workspace layout (bytes) ----------------
static constexpr size_t OFF_TOFF = 128;                                 // 9 int
static constexpr size_t OFF_ZBUF = 4096;                                // 4KB zeros
static constexpr size_t OFF_T2E  = 8192;                                // N*2 int
static constexpr size_t OFF_T2G  = OFF_T2E + (size_t)NTOK * TOPK * 4;   // N*2 f32
static constexpr size_t OFF_SLOT = OFF_T2G + (size_t)NTOK * TOPK * 4;   // N*2 int
static constexpr size_t OFF_TOK  = OFF_SLOT + (size_t)NTOK * TOPK * 4;  // CAPS int
static constexpr size_t OFF_GAT  = OFF_TOK + (size_t)CAPS * 4;          // CAPS f32
static constexpr size_t OFF_XB   = (OFF_GAT + (size_t)CAPS * 4 + 255) & ~(size_t)255;
static constexpr size_t OFF_W1T  = OFF_XB  + (size_t)NTOK * DDIM * 2;   // [E][H][D] bf16
static constexpr size_t OFF_W2T  = OFF_W1T + (size_t)NEXP * DDIM * HDIM * 2;
static constexpr size_t OFF_W3T  = OFF_W2T + (size_t)NEXP * HDIM * HDIM * 2;
static constexpr size_t OFF_H2   = OFF_W3T + (size_t)NEXP * HDIM * DDIM * 2; // [CAPS][H]
static constexpr size_t OFF_H3   = OFF_H2  + (size_t)CAPS * HDIM * 2;   // [CAPS][D] bf16

static __device__ __forceinline__ unsigned short f2b(float f) {
    __bf16 h = (__bf16)f;
    return __builtin_bit_cast(unsigned short, h);
}
static __device__ __forceinline__ float b2f(unsigned short u) {
    return __builtin_bit_cast(float, ((unsigned)u) << 16);
}

// ---------------------------------------------------------------------------
// Fused: [gating + x->bf16 conversion]  ||  [all weight transposes].
// Grid dim3(832, 8). Block-uniform branch on blockIdx.x.  (R7/R11-verified.)
// ---------------------------------------------------------------------------
__global__ __launch_bounds__(256) void gate_trans(
    const float* __restrict__ x, const float* __restrict__ Wg,
    const float* __restrict__ bg, unsigned short* __restrict__ xb,
    int* __restrict__ top2e, float* __restrict__ top2g,
    const float* __restrict__ W1, const float* __restrict__ W2,
    const float* __restrict__ W3, __bf16* __restrict__ w1t,
    __bf16* __restrict__ w2t, __bf16* __restrict__ w3t)
{
    __shared__ __align__(16) float sh[NEXP * DDIM];   // 32KB
    const int tid = threadIdx.x;

    if (blockIdx.x < 256) {
        // ---------------- gate + convert ----------------
        for (int d = tid; d < DDIM; d += 256) {
            const float4 w0 = *(const float4*)(Wg + (size_t)d * NEXP);
            const float4 w1 = *(const float4*)(Wg + (size_t)d * NEXP + 4);
            sh[0 * DDIM + d] = w0.x; sh[1 * DDIM + d] = w0.y;
            sh[2 * DDIM + d] = w0.z; sh[3 * DDIM + d] = w0.w;
            sh[4 * DDIM + d] = w1.x; sh[5 * DDIM + d] = w1.y;
            sh[6 * DDIM + d] = w1.z; sh[7 * DDIM + d] = w1.w;
        }
        __syncthreads();

        const int n = (blockIdx.y * 256 + blockIdx.x) * 4 + (tid >> 6);
        const int lane = tid & 63;
        const float* xr = x + (size_t)n * DDIM;
        unsigned short* xbr = xb + (size_t)n * DDIM;

        float acc[NEXP];
#pragma unroll
        for (int e = 0; e < NEXP; ++e) acc[e] = 0.f;

#pragma unroll
        for (int it = 0; it < 4; ++it) {
            const int d = it * 256 + lane * 4;
            const float4 xv = *(const float4*)(xr + d);
            ushort4 u;
            u.x = f2b(xv.x); u.y = f2b(xv.y); u.z = f2b(xv.z); u.w = f2b(xv.w);
            *(ushort4*)(xbr + d) = u;
#pragma unroll
            for (int e = 0; e < NEXP; ++e) {
                const float4 wt = *(const float4*)(sh + e * DDIM + d);
                acc[e] = fmaf(xv.x, wt.x, acc[e]);
                acc[e] = fmaf(xv.y, wt.y, acc[e]);
                acc[e] = fmaf(xv.z, wt.z, acc[e]);
                acc[e] = fmaf(xv.w, wt.w, acc[e]);
            }
        }
#pragma unroll
        for (int off = 32; off > 0; off >>= 1)
#pragma unroll
            for (int e = 0; e < NEXP; ++e) acc[e] += __shfl_down(acc[e], off, 64);

        if (lane == 0) {
            float v[NEXP], mx = -1e30f;
#pragma unroll
            for (int e = 0; e < NEXP; ++e) { v[e] = acc[e] + bg[e]; mx = fmaxf(mx, v[e]); }
            float p[NEXP], s = 0.f;
#pragma unroll
            for (int e = 0; e < NEXP; ++e) { p[e] = expf(v[e] - mx); s += p[e]; }
            const float inv = 1.f / s;
#pragma unroll
            for (int e = 0; e < NEXP; ++e) p[e] *= inv;
            int i0 = 0;
#pragma unroll
            for (int e = 1; e < NEXP; ++e) if (p[e] > p[i0]) i0 = e;
            int i1 = (i0 == 0) ? 1 : 0;
#pragma unroll
            for (int e = 0; e < NEXP; ++e) if (e != i0 && p[e] > p[i1]) i1 = e;
            top2e[n * 2 + 0] = i0;  top2e[n * 2 + 1] = i1;
            top2g[n * 2 + 0] = p[i0]; top2g[n * 2 + 1] = p[i1];
        }
    } else {
        // ---------------- weight transpose ----------------
        const int e = blockIdx.y;
        int bt = blockIdx.x - 256;
        const float* Wi; __bf16* Wo; int R, C, xt, yt;
        if (bt < 256)      { Wi = W1; Wo = w1t; R = DDIM; C = HDIM; xt = bt & 7;  yt = bt >> 3; }
        else if (bt < 320) { bt -= 256; Wi = W2; Wo = w2t; R = HDIM; C = HDIM; xt = bt & 7;  yt = bt >> 3; }
        else               { bt -= 320; Wi = W3; Wo = w3t; R = HDIM; C = DDIM; xt = bt & 31; yt = bt >> 5; }
        const int r0 = yt * 32, c0 = xt * 32;
        const int tx = tid & 31, ty = tid >> 5;  // 32 x 8
        const float* Wie = Wi + (size_t)e * R * C;
        __bf16* Woe = Wo + (size_t)e * C * R;
#pragma unroll
        for (int j = 0; j < 4; ++j)
            sh[(ty + j * 8) * 33 + tx] = Wie[(size_t)(r0 + ty + j * 8) * C + c0 + tx];
        __syncthreads();
#pragma unroll
        for (int j = 0; j < 4; ++j)
            Woe[(size_t)(c0 + ty + j * 8) * R + r0 + tx] = (__bf16)sh[tx * 33 + ty + j * 8];
    }
}

// ---------------------------------------------------------------------------
// route: ONE block, 1024 threads; scan-based slot assignment, no atomics.
// (R7/R11-verified.)
// ---------------------------------------------------------------------------
__global__ __launch_bounds__(1024) void route(
    const int* __restrict__ top2e, const float* __restrict__ top2g,
    int* __restrict__ toff, int* __restrict__ tok, float* __restrict__ gat,
    int* __restrict__ slotof, float* __restrict__ zbuf)
{
    const int tid = threadIdx.x;
    const int wv = tid >> 6, ln = tid & 63;
    __shared__ int   waveTot[16][NEXP];
    __shared__ int   waveBase[16][NEXP];
    __shared__ int   totS[NEXP];
    __shared__ int   toffS[NEXP + 1];
    __shared__ short excS[1024][NEXP];   // wave-exclusive rank, 16KB

    zbuf[tid] = 0.f;                     // 4KB zero page for pad-row gathers

    int myE[16]; float myG[16];
    const int4*   pe = (const int4*)(top2e + tid * 16);
    const float4* pg = (const float4*)(top2g + tid * 16);
#pragma unroll
    for (int q = 0; q < 4; ++q) {
        const int4 v = pe[q];
        myE[q * 4 + 0] = v.x; myE[q * 4 + 1] = v.y;
        myE[q * 4 + 2] = v.z; myE[q * 4 + 3] = v.w;
        const float4 g = pg[q];
        myG[q * 4 + 0] = g.x; myG[q * 4 + 1] = g.y;
        myG[q * 4 + 2] = g.z; myG[q * 4 + 3] = g.w;
    }

#pragma unroll
    for (int e = 0; e < NEXP; ++e) {
        int c = 0;
#pragma unroll
        for (int j = 0; j < 16; ++j) c += (myE[j] == e);
        int inc = c;
#pragma unroll
        for (int off = 1; off < 64; off <<= 1) {
            const int t = __shfl_up(inc, off, 64);
            if (ln >= off) inc += t;
        }
        excS[tid][e] = (short)(inc - c);
        if (ln == 63) waveTot[wv][e] = inc;
    }
    __syncthreads();

    if (tid < NEXP) {          // tid = expert id
        int b = 0;
#pragma unroll
        for (int w = 0; w < 16; ++w) {
            const int t = waveTot[w][tid];
            waveBase[w][tid] = b;
            b += t;
        }
        totS[tid] = b;
    }
    __syncthreads();

    if (tid == 0) {
        int acc = 0;
#pragma unroll
        for (int e = 0; e < NEXP; ++e) {
            toffS[e] = acc;
            acc += (totS[e] + PADM - 1) & ~(PADM - 1);
        }
        toffS[NEXP] = acc;
#pragma unroll
        for (int e = 0; e <= NEXP; ++e) toff[e] = toffS[e];
    }
    __syncthreads();

    // scatter entries to slots
#pragma unroll
    for (int j = 0; j < 16; ++j) {
        int pre = 0;
#pragma unroll
        for (int j2 = 0; j2 < j; ++j2) pre += (myE[j2] == myE[j]);
        const int e = myE[j];
        const int slot = toffS[e] + waveBase[wv][e] + (int)excS[tid][e] + pre;
        const int i = tid * 16 + j;
        tok[slot] = i >> 1;
        gat[slot] = myG[j];
        slotof[i] = slot;
    }

    // fill padding slots: tok=-1 -> zero-page gather; gat=0.
#pragma unroll
    for (int e = 0; e < NEXP; ++e) {
        const int begin = toffS[e] + totS[e];
        const int end   = toffS[e + 1];
        for (int i = begin + tid; i < end; i += 1024) {
            tok[i] = -1;
            gat[i] = 0.f;
        }
    }
}

// ---------------------------------------------------------------------------
// Fused L1+L2 grouped GEMM, BM=32, COUNTED-VMCNT 2-deep pipeline (T4).
// 4 waves x (32 rows x 64 cols), BK=64.
// Per step: issue next stage (9 GLDS/thread) -> vmcnt(9) waits only for the
// PREVIOUS stage (next stays in flight through MFMA) -> raw s_barrier ->
// compute -> s_barrier. Phase transitions prefetch the next phase's first
// panel; the L1->L2 epilogue barrier waits only lgkmcnt (prefetch survives).
// LDS: As 2x4K | Bs 2x32K | H1s 16K = 88KB -> 1 block/CU (m201 precedent:
// deep pipelines win at 1 block/CU; R13's failure was drain semantics).
// ---------------------------------------------------------------------------
__global__ __launch_bounds__(256) void egemm12(
    const __bf16* __restrict__ xb, const __bf16* __restrict__ w1t,
    const __bf16* __restrict__ w2t, const float* __restrict__ b1,
    const float* __restrict__ b2, const int* __restrict__ toff,
    const int* __restrict__ tok, const char* __restrict__ zbuf,
    __bf16* __restrict__ h2)
{
    const int total = toff[NEXP];
    const int slot0 = blockIdx.x * 32;
    if (slot0 >= total) return;
    int e = 0;
    while (toff[e + 1] <= slot0) ++e;

    __shared__ __align__(16) char smem[90112];
    char* AsB = smem;            // 2 x [32][64] bf16 swizzled (4KB each)
    char* BsB = smem + 8192;     // 2 x [256][64] bf16 swizzled (32KB each)
    char* H1s = smem + 73728;    // [32][256] bf16 swizzled (16KB)

    const int tid  = threadIdx.x;
    const int lane = tid & 63;
    const int wid  = tid >> 6;           // wave = col strip (64 cols)

    const int srow  = tid >> 3;          // 0..31
    const int sslot = tid & 7;
    const int ks    = sslot ^ (srow & 7);  // inverse-swizzled 16B slot

    const __bf16* We1 = w1t + (size_t)e * HDIM * DDIM;   // [256][1024]
    const __bf16* We2 = w2t + (size_t)e * HDIM * HDIM;   // [256][256]
    const int t0 = tok[slot0 + srow];
    const char* ap = (t0 >= 0) ? (const char*)(xb + (size_t)t0 * DDIM + ks * 8)
                               : (const char*)zbuf;
    const char* bp1[8];
    const char* bp2[8];
#pragma unroll
    for (int i = 0; i < 8; ++i) {
        bp1[i] = (const char*)(We1 + (size_t)(i * 32 + srow) * DDIM + ks * 8);
        bp2[i] = (const char*)(We2 + (size_t)(i * 32 + srow) * HDIM + ks * 8);
    }

    const int llo = lane & 15, lhi = lane >> 4;
    const int m7 = llo & 7;
    int abyte[2], bbyte[4];
#pragma unroll
    for (int m = 0; m < 2; ++m) abyte[m] = (m * 16 + llo) * 128;
#pragma unroll
    for (int n = 0; n < 4; ++n) bbyte[n] = (wid * 64 + n * 16 + llo) * 128;

    // staging helpers: 9 / 8 GLDS per thread respectively
    auto stage1 = [&](int t, int b) {
        const size_t kb = (size_t)t * 128;
        GLDS16(ap + kb, AsB + b * 4096 + tid * 16);
#pragma unroll
        for (int i = 0; i < 8; ++i)
            GLDS16(bp1[i] + kb, BsB + b * 32768 + i * 4096 + tid * 16);
    };
    auto stage2 = [&](int k2, int b) {
        const size_t kb = (size_t)k2 * 128;
#pragma unroll
        for (int i = 0; i < 8; ++i)
            GLDS16(bp2[i] + kb, BsB + b * 32768 + i * 4096 + tid * 16);
    };

    f32x4 acc[2][4];
#pragma unroll
    for (int m = 0; m < 2; ++m)
#pragma unroll
        for (int n = 0; n < 4; ++n) acc[m][n] = (f32x4){0.f, 0.f, 0.f, 0.f};

    // =================== L1: 16 steps, K=1024, counted pipeline ============
    stage1(0, 0);                                // 9 outstanding
    for (int t = 0; t < 16; ++t) {
        const int cb = t & 1, nb = cb ^ 1;
        if (t < 15) { stage1(t + 1, nb); VMCNT9; }   // wait stage(t) only
        else        { stage2(0, nb);     VMCNT8; }   // L2 prefetch stays live
        SBAR(); SCHED0();
#pragma unroll
        for (int kk = 0; kk < 2; ++kk) {
            const int sl = ((kk << 2) + lhi) ^ m7;
            bf16x8 af[2], bfr[4];
#pragma unroll
            for (int m = 0; m < 2; ++m)
                af[m]  = *(const bf16x8*)(AsB + cb * 4096 + abyte[m] + (sl << 4));
#pragma unroll
            for (int n = 0; n < 4; ++n)
                bfr[n] = *(const bf16x8*)(BsB + cb * 32768 + bbyte[n] + (sl << 4));
#pragma unroll
            for (int m = 0; m < 2; ++m)
#pragma unroll
                for (int n = 0; n < 4; ++n)
                    acc[m][n] = __builtin_amdgcn_mfma_f32_16x16x32_bf16(
                        af[m], bfr[n], acc[m][n], 0, 0, 0);
        }
        SCHED0(); SBAR();
    }

    // ---- L1 epilogue: relu+bias -> H1s; barrier waits LDS only ----
    {
        const float* be1 = b1 + (size_t)e * HDIM;
#pragma unroll
        for (int n = 0; n < 4; ++n) {
            const int col = wid * 64 + n * 16 + llo;
            const float bb = be1[col];
            const int colbyte = (col & 7) * 2;
            const int slice = col >> 3;
#pragma unroll
            for (int m = 0; m < 2; ++m) {
#pragma unroll
                for (int j = 0; j < 4; ++j) {
                    const int r = m * 16 + lhi * 4 + j;
                    const float v = fmaxf(acc[m][n][j] + bb, 0.f);
                    *(__bf16*)(H1s + r * 512 + ((slice ^ (r & 7)) << 4) + colbyte) = (__bf16)v;
                }
                acc[m][n] = (f32x4){0.f, 0.f, 0.f, 0.f};
            }
        }
    }
    LGKM0; SBAR(); SCHED0();

    // =================== L2: 4 steps, K=256 (A from H1s) ===================
    for (int k2 = 0; k2 < 4; ++k2) {
        const int cb = k2 & 1, nb = cb ^ 1;
        if (k2 < 3) { stage2(k2 + 1, nb); VMCNT8; }
        else        { VMCNT0; }
        SBAR(); SCHED0();
#pragma unroll
        for (int kk = 0; kk < 2; ++kk) {
            const int slB = ((kk << 2) + lhi) ^ m7;
            const int slA = (k2 * 8 + (kk << 2) + lhi) ^ m7;
            bf16x8 af[2], bfr[4];
#pragma unroll
            for (int m = 0; m < 2; ++m)
                af[m] = *(const bf16x8*)(H1s + (m * 16 + llo) * 512 + (slA << 4));
#pragma unroll
            for (int n = 0; n < 4; ++n)
                bfr[n] = *(const bf16x8*)(BsB + cb * 32768 + bbyte[n] + (slB << 4));
#pragma unroll
            for (int m = 0; m < 2; ++m)
#pragma unroll
                for (int n = 0; n < 4; ++n)
                    acc[m][n] = __builtin_amdgcn_mfma_f32_16x16x32_bf16(
                        af[m], bfr[n], acc[m][n], 0, 0, 0);
        }
        SCHED0(); SBAR();
    }

    // ---- L2 epilogue: relu+bias -> h2 global bf16 ----
    {
        const float* be2 = b2 + (size_t)e * HDIM;
#pragma unroll
        for (int n = 0; n < 4; ++n) {
            const int col = wid * 64 + n * 16 + llo;
            const float bb = be2[col];
#pragma unroll
            for (int m = 0; m < 2; ++m) {
#pragma unroll
                for (int j = 0; j < 4; ++j) {
                    const int r = slot0 + m * 16 + lhi * 4 + j;
                    h2[(size_t)r * HDIM + col] = (__bf16)fmaxf(acc[m][n][j] + bb, 0.f);
                }
            }
        }
    }
}

// ---------------------------------------------------------------------------
// Grouped bf16 MFMA GEMM (layer 3). 128x128 tile, 4 waves x (64x64), BK=64.
// Counted-vmcnt 2-deep pipeline (same pattern as egemm12). Dbuf 64KB LDS.
// Grid: dim3(NCOL/128, NT128) — col-tile on fast axis (A re-reads hit L2).
// ---------------------------------------------------------------------------
template<int KDIM, int NCOL>
__global__ __launch_bounds__(256) void egemm3(
    const __bf16* __restrict__ Ain, const __bf16* __restrict__ Wt,
    const float* __restrict__ ball, const int* __restrict__ toff,
    const float* __restrict__ gat, __bf16* __restrict__ Out)
{
    const int total = toff[NEXP];
    const int slot0 = blockIdx.y * 128;
    if (slot0 >= total) return;
    int e = 0;
    while (toff[e + 1] <= slot0) ++e;
    const int col0 = blockIdx.x * 128;

    __shared__ __align__(16) char smem[65536];
    char* AsB = smem;            // 2 x [128][64] bf16, swizzled (16KB each)
    char* BsB = smem + 32768;    // 2 x [128][64] bf16, swizzled (16KB each)

    const int tid  = threadIdx.x;
    const int lane = tid & 63;
    const int wid  = tid >> 6;
    const int wr = wid >> 1, wc = wid & 1;

    const int srow  = tid >> 3;
    const int sslot = tid & 7;
    const int ks    = sslot ^ (srow & 7);
    const __bf16* We = Wt + (size_t)e * NCOL * KDIM;
    const char* ap[4];
    const char* bp[4];
#pragma unroll
    for (int i = 0; i < 4; ++i) {
        const int row = i * 32 + srow;
        ap[i] = (const char*)(Ain + (size_t)(slot0 + row) * KDIM + ks * 8);
        bp[i] = (const char*)(We + (size_t)(col0 + row) * KDIM + ks * 8);
    }

    const int llo = lane & 15, lhi = lane >> 4;
    const int m7 = llo & 7;
    int abyte[4], bbyte[4];
#pragma unroll
    for (int m = 0; m < 4; ++m) {
        abyte[m] = (wr * 64 + m * 16 + llo) * 128;
        bbyte[m] = (wc * 64 + m * 16 + llo) * 128;
    }

    auto stageK = [&](int k, int b) {     // 8 GLDS per thread
        const size_t kb = (size_t)k * 128;
#pragma unroll
        for (int i = 0; i < 4; ++i)
            GLDS16(ap[i] + kb, AsB + b * 16384 + i * 4096 + wid * 1024);
#pragma unroll
        for (int i = 0; i < 4; ++i)
            GLDS16(bp[i] + kb, BsB + b * 16384 + i * 4096 + wid * 1024);
    };

    f32x4 acc[4][4];
#pragma unroll
    for (int m = 0; m < 4; ++m)
#pragma unroll
        for (int n = 0; n < 4; ++n) acc[m][n] = (f32x4){0.f, 0.f, 0.f, 0.f};

    stageK(0, 0);                                 // 8 outstanding
    for (int k = 0; k < KDIM / 64; ++k) {
        const int cb = k & 1, nb = cb ^ 1;
        if (k < KDIM / 64 - 1) { stageK(k + 1, nb); VMCNT8; }
        else                   { VMCNT0; }
        SBAR(); SCHED0();
#pragma unroll
        for (int kk = 0; kk < 2; ++kk) {
            const int sl = ((kk << 2) + lhi) ^ m7;
            bf16x8 af[4], bfr[4];
#pragma unroll
            for (int m = 0; m < 4; ++m)
                af[m]  = *(const bf16x8*)(AsB + cb * 16384 + abyte[m] + (sl << 4));
#pragma unroll
            for (int n = 0; n < 4; ++n)
                bfr[n] = *(const bf16x8*)(BsB + cb * 16384 + bbyte[n] + (sl << 4));
#pragma unroll
            for (int m = 0; m < 4; ++m)
#pragma unroll
                for (int n = 0; n < 4; ++n)
                    acc[m][n] = __builtin_amdgcn_mfma_f32_16x16x32_bf16(
                        af[m], bfr[n], acc[m][n], 0, 0, 0);
        }
        SCHED0(); SBAR();
    }

    const float* be = ball + (size_t)e * NCOL;
#pragma unroll
    for (int m = 0; m < 4; ++m) {
        const int rbase = slot0 + wr * 64 + m * 16 + lhi * 4;
        float g[4];
#pragma unroll
        for (int j = 0; j < 4; ++j) g[j] = gat[rbase + j];
#pragma unroll
        for (int n = 0; n < 4; ++n) {
            const int col = col0 + wc * 64 + n * 16 + llo;
            const float bb = be[col];
#pragma unroll
            for (int j = 0; j < 4; ++j) {
                const float v = fmaxf(acc[m][n][j] + bb, 0.f) * g[j];
                Out[(size_t)(rbase + j) * NCOL + col] = (__bf16)v;
            }
        }
    }
}

// ---------------------------------------------------------------------------
// Combine: out[n][d] = h3[s0][d] + h3[s1][d]  (gates already applied in L3).
// ---------------------------------------------------------------------------
__global__ __launch_bounds__(256) void combine(
    const unsigned short* __restrict__ h3, const int* __restrict__ slotof,
    float* __restrict__ out)
{
    const int n = blockIdx.x;
    const int c = threadIdx.x * 4;
    const int s0 = slotof[n * 2], s1 = slotof[n * 2 + 1];
    const ushort4 a = *(const ushort4*)(h3 + (size_t)s0 * DDIM + c);
    const ushort4 b = *(const ushort4*)(h3 + (size_t)s1 * DDIM + c);
    float4 o;
    o.x = b2f(a.x) + b2f(b.x);
    o.y = b2f(a.y) + b2f(b.y);
    o.z = b2f(a.z) + b2f(b.z);
    o.w = b2f(a.w) + b2f(b.w);
    *(float4*)(out + (size_t)n * DDIM + c) = o;
}

extern "C" void kernel_launch(void* const* d_in, const int* in_sizes, int n_in,
                              void* d_out, int out_size, void* d_ws, size_t ws_size,
                              hipStream_t stream)
{
    const float* x  = (const float*)d_in[0];
    const float* Wg = (const float*)d_in[1];
    const float* bg = (const float*)d_in[2];
    const float* W1 = (const float*)d_in[3];
    const float* b1 = (const float*)d_in[4];
    const float* W2 = (const float*)d_in[5];
    const float* b2 = (const float*)d_in[6];
    const float* W3 = (const float*)d_in[7];
    const float* b3 = (const float*)d_in[8];
    float* out = (float*)d_out;

    char* ws = (char*)d_ws;
    int*   toff   = (int*)(ws + OFF_TOFF);
    char*  zbuf   = ws + OFF_ZBUF;
    int*   top2e  = (int*)(ws + OFF_T2E);
    float* top2g  = (float*)(ws + OFF_T2G);
    int*   slotof = (int*)(ws + OFF_SLOT);
    int*   tok    = (int*)(ws + OFF_TOK);
    float* gat    = (float*)(ws + OFF_GAT);
    unsigned short* xbu = (unsigned short*)(ws + OFF_XB);
    __bf16* xb  = (__bf16*)(ws + OFF_XB);
    __bf16* w1t = (__bf16*)(ws + OFF_W1T);
    __bf16* w2t = (__bf16*)(ws + OFF_W2T);
    __bf16* w3t = (__bf16*)(ws + OFF_W3T);
    __bf16* h2  = (__bf16*)(ws + OFF_H2);
    __bf16* h3  = (__bf16*)(ws + OFF_H3);

    // fused: gating + x->bf16 conversion || weight transposes (concurrent)
    gate_trans<<<dim3(832, NEXP), 256, 0, stream>>>(
        x, Wg, bg, xbu, top2e, top2g, W1, W2, W3, w1t, w2t, w3t);
    // routing (no atomics, no memsets)
    route<<<1, 1024, 0, stream>>>(top2e, top2g, toff, tok, gat, slotof, (float*)zbuf);

    // expert MLP: fused L1+L2 (BM=32, counted-vmcnt pipeline), then L3
    egemm12<<<NT32, 256, 0, stream>>>(xb, w1t, w2t, b1, b2, toff, tok, zbuf, h2);
    egemm3<HDIM, DDIM><<<dim3(DDIM / 128, NT128), 256, 0, stream>>>(
        h2, w3t, b3, toff, gat, h3);

    // combine the two expert contributions per token
    combine<<<NTOK, 256, 0, stream>>>((const unsigned short*)h3, slotof, out);
}

// Round 16
// 104.821 us; speedup vs baseline: 1.0800x; 1.0800x over previous
//
#include <hip/hip_runtime.h>
#include <math.h>

// Problem constants
#define NTOK 8192
#define DDIM 1024
#define NEXP 8
#define HDIM 256
#define TOPK 2
#define PADM 128                         // per-expert row padding
#define CAPS (NTOK * TOPK + NEXP * PADM) // 17408 slots max
#define NT32  (CAPS / 32)                // 544 row tiles (BM=32, egemm12)
#define NT128 (CAPS / 128)               // 136 row tiles (BM=128, egemm3)

typedef __attribute__((ext_vector_type(8))) __bf16 bf16x8;
typedef __attribute__((ext_vector_type(4))) float f32x4;

#define GLDS16(g, s)                                                      \
    __builtin_amdgcn_global_load_lds(                                     \
        (const __attribute__((address_space(1))) void*)(g),               \
        (__attribute__((address_space(3))) void*)(s), 16, 0, 0)

// ---------------- workspace layout (bytes) ----------------
static constexpr size_t OFF_TOFF = 128;                                 // 9 int
static constexpr size_t OFF_ZBUF = 4096;                                // 4KB zeros
static constexpr size_t OFF_T2E  = 8192;                                // N*2 int
static constexpr size_t OFF_T2G  = OFF_T2E + (size_t)NTOK * TOPK * 4;   // N*2 f32
static constexpr size_t OFF_SLOT = OFF_T2G + (size_t)NTOK * TOPK * 4;   // N*2 int
static constexpr size_t OFF_TOK  = OFF_SLOT + (size_t)NTOK * TOPK * 4;  // CAPS int
static constexpr size_t OFF_GAT  = OFF_TOK + (size_t)CAPS * 4;          // CAPS f32
static constexpr size_t OFF_XB   = (OFF_GAT + (size_t)CAPS * 4 + 255) & ~(size_t)255;
static constexpr size_t OFF_W1T  = OFF_XB  + (size_t)NTOK * DDIM * 2;   // [E][H][D] bf16
static constexpr size_t OFF_W2T  = OFF_W1T + (size_t)NEXP * DDIM * HDIM * 2;
static constexpr size_t OFF_W3T  = OFF_W2T + (size_t)NEXP * HDIM * HDIM * 2;
static constexpr size_t OFF_H2   = OFF_W3T + (size_t)NEXP * HDIM * DDIM * 2; // [CAPS][H]
static constexpr size_t OFF_H3   = OFF_H2  + (size_t)CAPS * HDIM * 2;   // [CAPS][D] bf16

static __device__ __forceinline__ unsigned short f2b(float f) {
    __bf16 h = (__bf16)f;
    return __builtin_bit_cast(unsigned short, h);
}
static __device__ __forceinline__ float b2f(unsigned short u) {
    return __builtin_bit_cast(float, ((unsigned)u) << 16);
}

// ---------------------------------------------------------------------------
// Fused: [gating + x->bf16 conversion]  ||  [all weight transposes].
// Grid dim3(832, 8). Block-uniform branch on blockIdx.x.  (R7/R11-verified.)
// ---------------------------------------------------------------------------
__global__ __launch_bounds__(256) void gate_trans(
    const float* __restrict__ x, const float* __restrict__ Wg,
    const float* __restrict__ bg, unsigned short* __restrict__ xb,
    int* __restrict__ top2e, float* __restrict__ top2g,
    const float* __restrict__ W1, const float* __restrict__ W2,
    const float* __restrict__ W3, __bf16* __restrict__ w1t,
    __bf16* __restrict__ w2t, __bf16* __restrict__ w3t)
{
    __shared__ __align__(16) float sh[NEXP * DDIM];   // 32KB
    const int tid = threadIdx.x;

    if (blockIdx.x < 256) {
        // ---------------- gate + convert ----------------
        for (int d = tid; d < DDIM; d += 256) {
            const float4 w0 = *(const float4*)(Wg + (size_t)d * NEXP);
            const float4 w1 = *(const float4*)(Wg + (size_t)d * NEXP + 4);
            sh[0 * DDIM + d] = w0.x; sh[1 * DDIM + d] = w0.y;
            sh[2 * DDIM + d] = w0.z; sh[3 * DDIM + d] = w0.w;
            sh[4 * DDIM + d] = w1.x; sh[5 * DDIM + d] = w1.y;
            sh[6 * DDIM + d] = w1.z; sh[7 * DDIM + d] = w1.w;
        }
        __syncthreads();

        const int n = (blockIdx.y * 256 + blockIdx.x) * 4 + (tid >> 6);
        const int lane = tid & 63;
        const float* xr = x + (size_t)n * DDIM;
        unsigned short* xbr = xb + (size_t)n * DDIM;

        float acc[NEXP];
#pragma unroll
        for (int e = 0; e < NEXP; ++e) acc[e] = 0.f;

#pragma unroll
        for (int it = 0; it < 4; ++it) {
            const int d = it * 256 + lane * 4;
            const float4 xv = *(const float4*)(xr + d);
            ushort4 u;
            u.x = f2b(xv.x); u.y = f2b(xv.y); u.z = f2b(xv.z); u.w = f2b(xv.w);
            *(ushort4*)(xbr + d) = u;
#pragma unroll
            for (int e = 0; e < NEXP; ++e) {
                const float4 wt = *(const float4*)(sh + e * DDIM + d);
                acc[e] = fmaf(xv.x, wt.x, acc[e]);
                acc[e] = fmaf(xv.y, wt.y, acc[e]);
                acc[e] = fmaf(xv.z, wt.z, acc[e]);
                acc[e] = fmaf(xv.w, wt.w, acc[e]);
            }
        }
#pragma unroll
        for (int off = 32; off > 0; off >>= 1)
#pragma unroll
            for (int e = 0; e < NEXP; ++e) acc[e] += __shfl_down(acc[e], off, 64);

        if (lane == 0) {
            float v[NEXP], mx = -1e30f;
#pragma unroll
            for (int e = 0; e < NEXP; ++e) { v[e] = acc[e] + bg[e]; mx = fmaxf(mx, v[e]); }
            float p[NEXP], s = 0.f;
#pragma unroll
            for (int e = 0; e < NEXP; ++e) { p[e] = expf(v[e] - mx); s += p[e]; }
            const float inv = 1.f / s;
#pragma unroll
            for (int e = 0; e < NEXP; ++e) p[e] *= inv;
            int i0 = 0;
#pragma unroll
            for (int e = 1; e < NEXP; ++e) if (p[e] > p[i0]) i0 = e;
            int i1 = (i0 == 0) ? 1 : 0;
#pragma unroll
            for (int e = 0; e < NEXP; ++e) if (e != i0 && p[e] > p[i1]) i1 = e;
            top2e[n * 2 + 0] = i0;  top2e[n * 2 + 1] = i1;
            top2g[n * 2 + 0] = p[i0]; top2g[n * 2 + 1] = p[i1];
        }
    } else {
        // ---------------- weight transpose ----------------
        const int e = blockIdx.y;
        int bt = blockIdx.x - 256;
        const float* Wi; __bf16* Wo; int R, C, xt, yt;
        if (bt < 256)      { Wi = W1; Wo = w1t; R = DDIM; C = HDIM; xt = bt & 7;  yt = bt >> 3; }
        else if (bt < 320) { bt -= 256; Wi = W2; Wo = w2t; R = HDIM; C = HDIM; xt = bt & 7;  yt = bt >> 3; }
        else               { bt -= 320; Wi = W3; Wo = w3t; R = HDIM; C = DDIM; xt = bt & 31; yt = bt >> 5; }
        const int r0 = yt * 32, c0 = xt * 32;
        const int tx = tid & 31, ty = tid >> 5;  // 32 x 8
        const float* Wie = Wi + (size_t)e * R * C;
        __bf16* Woe = Wo + (size_t)e * C * R;
#pragma unroll
        for (int j = 0; j < 4; ++j)
            sh[(ty + j * 8) * 33 + tx] = Wie[(size_t)(r0 + ty + j * 8) * C + c0 + tx];
        __syncthreads();
#pragma unroll
        for (int j = 0; j < 4; ++j)
            Woe[(size_t)(c0 + ty + j * 8) * R + r0 + tx] = (__bf16)sh[tx * 33 + ty + j * 8];
    }
}

// ---------------------------------------------------------------------------
// route: ONE block, 1024 threads; scan-based slot assignment, no atomics.
// (R7/R11-verified.)
// ---------------------------------------------------------------------------
__global__ __launch_bounds__(1024) void route(
    const int* __restrict__ top2e, const float* __restrict__ top2g,
    int* __restrict__ toff, int* __restrict__ tok, float* __restrict__ gat,
    int* __restrict__ slotof, float* __restrict__ zbuf)
{
    const int tid = threadIdx.x;
    const int wv = tid >> 6, ln = tid & 63;
    __shared__ int   waveTot[16][NEXP];
    __shared__ int   waveBase[16][NEXP];
    __shared__ int   totS[NEXP];
    __shared__ int   toffS[NEXP + 1];
    __shared__ short excS[1024][NEXP];   // wave-exclusive rank, 16KB

    zbuf[tid] = 0.f;                     // 4KB zero page for pad-row gathers

    int myE[16]; float myG[16];
    const int4*   pe = (const int4*)(top2e + tid * 16);
    const float4* pg = (const float4*)(top2g + tid * 16);
#pragma unroll
    for (int q = 0; q < 4; ++q) {
        const int4 v = pe[q];
        myE[q * 4 + 0] = v.x; myE[q * 4 + 1] = v.y;
        myE[q * 4 + 2] = v.z; myE[q * 4 + 3] = v.w;
        const float4 g = pg[q];
        myG[q * 4 + 0] = g.x; myG[q * 4 + 1] = g.y;
        myG[q * 4 + 2] = g.z; myG[q * 4 + 3] = g.w;
    }

#pragma unroll
    for (int e = 0; e < NEXP; ++e) {
        int c = 0;
#pragma unroll
        for (int j = 0; j < 16; ++j) c += (myE[j] == e);
        int inc = c;
#pragma unroll
        for (int off = 1; off < 64; off <<= 1) {
            const int t = __shfl_up(inc, off, 64);
            if (ln >= off) inc += t;
        }
        excS[tid][e] = (short)(inc - c);
        if (ln == 63) waveTot[wv][e] = inc;
    }
    __syncthreads();

    if (tid < NEXP) {          // tid = expert id
        int b = 0;
#pragma unroll
        for (int w = 0; w < 16; ++w) {
            const int t = waveTot[w][tid];
            waveBase[w][tid] = b;
            b += t;
        }
        totS[tid] = b;
    }
    __syncthreads();

    if (tid == 0) {
        int acc = 0;
#pragma unroll
        for (int e = 0; e < NEXP; ++e) {
            toffS[e] = acc;
            acc += (totS[e] + PADM - 1) & ~(PADM - 1);
        }
        toffS[NEXP] = acc;
#pragma unroll
        for (int e = 0; e <= NEXP; ++e) toff[e] = toffS[e];
    }
    __syncthreads();

    // scatter entries to slots
#pragma unroll
    for (int j = 0; j < 16; ++j) {
        int pre = 0;
#pragma unroll
        for (int j2 = 0; j2 < j; ++j2) pre += (myE[j2] == myE[j]);
        const int e = myE[j];
        const int slot = toffS[e] + waveBase[wv][e] + (int)excS[tid][e] + pre;
        const int i = tid * 16 + j;
        tok[slot] = i >> 1;
        gat[slot] = myG[j];
        slotof[i] = slot;
    }

    // fill padding slots: tok=-1 -> zero-page gather; gat=0.
#pragma unroll
    for (int e = 0; e < NEXP; ++e) {
        const int begin = toffS[e] + totS[e];
        const int end   = toffS[e + 1];
        for (int i = begin + tid; i < end; i += 1024) {
            tok[i] = -1;
            gat[i] = 0.f;
        }
    }
}

// ---------------------------------------------------------------------------
// Fused L1+L2 grouped GEMM, BM=32 (R14-verified best).
// 4 waves x (32 rows x 64 cols), BK=64.
// LDS: As 4KB | Bs 32KB | H1s 16KB = 52KB -> 3 blocks/CU resident capacity.
//   L1: h1 = relu(xb[gather] @ W1T^T + b1)  -> H1s LDS (swizzled)
//   L2: h2 = relu(h1 @ W2T^T + b2)          -> global bf16
// ---------------------------------------------------------------------------
__global__ __launch_bounds__(256) void egemm12(
    const __bf16* __restrict__ xb, const __bf16* __restrict__ w1t,
    const __bf16* __restrict__ w2t, const float* __restrict__ b1,
    const float* __restrict__ b2, const int* __restrict__ toff,
    const int* __restrict__ tok, const char* __restrict__ zbuf,
    __bf16* __restrict__ h2)
{
    const int total = toff[NEXP];
    const int slot0 = blockIdx.x * 32;
    if (slot0 >= total) return;
    int e = 0;
    while (toff[e + 1] <= slot0) ++e;

    __shared__ __align__(16) char smem[53248];
    char* AsB = smem;            // [32 rows][64 k] bf16, swizzled (4KB)
    char* BsB = smem + 4096;     // [256 rows][64 k] bf16, swizzled (32KB)
    char* H1s = smem + 36864;    // [32 rows][256 h] bf16, swizzled (16KB)

    const int tid  = threadIdx.x;
    const int lane = tid & 63;
    const int wid  = tid >> 6;           // wave = col strip (64 cols)

    const int srow  = tid >> 3;          // 0..31
    const int sslot = tid & 7;
    const int ks    = sslot ^ (srow & 7);  // inverse-swizzled 16B slot

    const __bf16* We1 = w1t + (size_t)e * HDIM * DDIM;   // [256][1024]
    const int t = tok[slot0 + srow];
    const char* ap = (t >= 0) ? (const char*)(xb + (size_t)t * DDIM + ks * 8)
                              : (const char*)zbuf;
    const char* bp1[8];
#pragma unroll
    for (int i = 0; i < 8; ++i)
        bp1[i] = (const char*)(We1 + (size_t)(i * 32 + srow) * DDIM + ks * 8);

    const int llo = lane & 15, lhi = lane >> 4;
    const int m7 = llo & 7;
    int abyte[2], bbyte[4];
#pragma unroll
    for (int m = 0; m < 2; ++m) abyte[m] = (m * 16 + llo) * 128;
#pragma unroll
    for (int n = 0; n < 4; ++n) bbyte[n] = (wid * 64 + n * 16 + llo) * 128;

    f32x4 acc[2][4];
#pragma unroll
    for (int m = 0; m < 2; ++m)
#pragma unroll
        for (int n = 0; n < 4; ++n) acc[m][n] = (f32x4){0.f, 0.f, 0.f, 0.f};

    // =================== L1: K=1024 ===================
    for (int k0 = 0; k0 < DDIM; k0 += 64) {
        const size_t kb = (size_t)k0 * 2;
        GLDS16(ap + kb, AsB + tid * 16);
#pragma unroll
        for (int i = 0; i < 8; ++i)
            GLDS16(bp1[i] + kb, BsB + i * 4096 + tid * 16);
        __syncthreads();
#pragma unroll
        for (int kk = 0; kk < 2; ++kk) {
            const int sl = ((kk << 2) + lhi) ^ m7;
            bf16x8 af[2], bfr[4];
#pragma unroll
            for (int m = 0; m < 2; ++m) af[m]  = *(const bf16x8*)(AsB + abyte[m] + (sl << 4));
#pragma unroll
            for (int n = 0; n < 4; ++n) bfr[n] = *(const bf16x8*)(BsB + bbyte[n] + (sl << 4));
#pragma unroll
            for (int m = 0; m < 2; ++m)
#pragma unroll
                for (int n = 0; n < 4; ++n)
                    acc[m][n] = __builtin_amdgcn_mfma_f32_16x16x32_bf16(
                        af[m], bfr[n], acc[m][n], 0, 0, 0);
        }
        __syncthreads();
    }

    // ---- L1 epilogue: relu+bias -> H1s (swizzled [32][256] bf16) ----
    {
        const float* be1 = b1 + (size_t)e * HDIM;
#pragma unroll
        for (int n = 0; n < 4; ++n) {
            const int col = wid * 64 + n * 16 + llo;
            const float bb = be1[col];
            const int colbyte = (col & 7) * 2;
            const int slice = col >> 3;
#pragma unroll
            for (int m = 0; m < 2; ++m) {
#pragma unroll
                for (int j = 0; j < 4; ++j) {
                    const int r = m * 16 + lhi * 4 + j;
                    const float v = fmaxf(acc[m][n][j] + bb, 0.f);
                    *(__bf16*)(H1s + r * 512 + ((slice ^ (r & 7)) << 4) + colbyte) = (__bf16)v;
                }
                acc[m][n] = (f32x4){0.f, 0.f, 0.f, 0.f};
            }
        }
    }
    __syncthreads();

    // =================== L2: K=256 (A from LDS) ===================
    const __bf16* We2 = w2t + (size_t)e * HDIM * HDIM;   // [256][256]
    const char* bp2[8];
#pragma unroll
    for (int i = 0; i < 8; ++i)
        bp2[i] = (const char*)(We2 + (size_t)(i * 32 + srow) * HDIM + ks * 8);

    for (int k2 = 0; k2 < 4; ++k2) {
        const size_t kb = (size_t)k2 * 128;
#pragma unroll
        for (int i = 0; i < 8; ++i)
            GLDS16(bp2[i] + kb, BsB + i * 4096 + tid * 16);
        __syncthreads();
#pragma unroll
        for (int kk = 0; kk < 2; ++kk) {
            const int slB = ((kk << 2) + lhi) ^ m7;
            const int slA = (k2 * 8 + (kk << 2) + lhi) ^ m7;
            bf16x8 af[2], bfr[4];
#pragma unroll
            for (int m = 0; m < 2; ++m)
                af[m] = *(const bf16x8*)(H1s + (m * 16 + llo) * 512 + (slA << 4));
#pragma unroll
            for (int n = 0; n < 4; ++n)
                bfr[n] = *(const bf16x8*)(BsB + bbyte[n] + (slB << 4));
#pragma unroll
            for (int m = 0; m < 2; ++m)
#pragma unroll
                for (int n = 0; n < 4; ++n)
                    acc[m][n] = __builtin_amdgcn_mfma_f32_16x16x32_bf16(
                        af[m], bfr[n], acc[m][n], 0, 0, 0);
        }
        __syncthreads();
    }

    // ---- L2 epilogue: relu+bias -> h2 global bf16 ----
    {
        const float* be2 = b2 + (size_t)e * HDIM;
#pragma unroll
        for (int n = 0; n < 4; ++n) {
            const int col = wid * 64 + n * 16 + llo;
            const float bb = be2[col];
#pragma unroll
            for (int m = 0; m < 2; ++m) {
#pragma unroll
                for (int j = 0; j < 4; ++j) {
                    const int r = slot0 + m * 16 + lhi * 4 + j;
                    h2[(size_t)r * HDIM + col] = (__bf16)fmaxf(acc[m][n][j] + bb, 0.f);
                }
            }
        }
    }
}

// ---------------------------------------------------------------------------
// Grouped bf16 MFMA GEMM (layer 3). 128x128 tile, 4 waves x (64x64), BK=64.
// Grid: dim3(NCOL/128, NT128) — col-tile on fast axis (A re-reads hit L2).
// (R7/R11/R14-verified.)
// ---------------------------------------------------------------------------
template<int KDIM, int NCOL>
__global__ __launch_bounds__(256) void egemm3(
    const __bf16* __restrict__ Ain, const __bf16* __restrict__ Wt,
    const float* __restrict__ ball, const int* __restrict__ toff,
    const float* __restrict__ gat, __bf16* __restrict__ Out)
{
    const int total = toff[NEXP];
    const int slot0 = blockIdx.y * 128;
    if (slot0 >= total) return;
    int e = 0;
    while (toff[e + 1] <= slot0) ++e;
    const int col0 = blockIdx.x * 128;

    __shared__ __align__(16) char smem[32768];
    char* AsB = smem;            // [128][64] bf16, swizzled
    char* BsB = smem + 16384;    // [128 n][64 k] bf16, swizzled

    const int tid  = threadIdx.x;
    const int lane = tid & 63;
    const int wid  = tid >> 6;
    const int wr = wid >> 1, wc = wid & 1;

    const int srow  = tid >> 3;
    const int sslot = tid & 7;
    const int ks    = sslot ^ (srow & 7);
    const __bf16* We = Wt + (size_t)e * NCOL * KDIM;
    const char* ap[4];
    const char* bp[4];
#pragma unroll
    for (int i = 0; i < 4; ++i) {
        const int row = i * 32 + srow;
        ap[i] = (const char*)(Ain + (size_t)(slot0 + row) * KDIM + ks * 8);
        bp[i] = (const char*)(We + (size_t)(col0 + row) * KDIM + ks * 8);
    }

    const int llo = lane & 15, lhi = lane >> 4;
    const int m7 = llo & 7;
    int abyte[4], bbyte[4];
#pragma unroll
    for (int m = 0; m < 4; ++m) {
        abyte[m] = (wr * 64 + m * 16 + llo) * 128;
        bbyte[m] = (wc * 64 + m * 16 + llo) * 128;
    }

    f32x4 acc[4][4];
#pragma unroll
    for (int m = 0; m < 4; ++m)
#pragma unroll
        for (int n = 0; n < 4; ++n) acc[m][n] = (f32x4){0.f, 0.f, 0.f, 0.f};

    for (int k0 = 0; k0 < KDIM; k0 += 64) {
        const size_t kb = (size_t)k0 * 2;
#pragma unroll
        for (int i = 0; i < 4; ++i)
            GLDS16(ap[i] + kb, AsB + i * 4096 + wid * 1024);
#pragma unroll
        for (int i = 0; i < 4; ++i)
            GLDS16(bp[i] + kb, BsB + i * 4096 + wid * 1024);
        __syncthreads();
#pragma unroll
        for (int kk = 0; kk < 2; ++kk) {
            const int sl = ((kk << 2) + lhi) ^ m7;
            bf16x8 af[4], bfr[4];
#pragma unroll
            for (int m = 0; m < 4; ++m) af[m]  = *(const bf16x8*)(AsB + abyte[m] + (sl << 4));
#pragma unroll
            for (int n = 0; n < 4; ++n) bfr[n] = *(const bf16x8*)(BsB + bbyte[n] + (sl << 4));
#pragma unroll
            for (int m = 0; m < 4; ++m)
#pragma unroll
                for (int n = 0; n < 4; ++n)
                    acc[m][n] = __builtin_amdgcn_mfma_f32_16x16x32_bf16(
                        af[m], bfr[n], acc[m][n], 0, 0, 0);
        }
        __syncthreads();
    }

    const float* be = ball + (size_t)e * NCOL;
#pragma unroll
    for (int m = 0; m < 4; ++m) {
        const int rbase = slot0 + wr * 64 + m * 16 + lhi * 4;
        float g[4];
#pragma unroll
        for (int j = 0; j < 4; ++j) g[j] = gat[rbase + j];
#pragma unroll
        for (int n = 0; n < 4; ++n) {
            const int col = col0 + wc * 64 + n * 16 + llo;
            const float bb = be[col];
#pragma unroll
            for (int j = 0; j < 4; ++j) {
                const float v = fmaxf(acc[m][n][j] + bb, 0.f) * g[j];
                Out[(size_t)(rbase + j) * NCOL + col] = (__bf16)v;
            }
        }
    }
}

// ---------------------------------------------------------------------------
// Combine: out[n][d] = h3[s0][d] + h3[s1][d]  (gates already applied in L3).
// R15 tweak (isolated): 4 tokens/block, one per wave -> 2048 blocks instead
// of 8192 (less launch/tail on a pure streaming kernel). Same per-token IO.
// ---------------------------------------------------------------------------
__global__ __launch_bounds__(256) void combine(
    const unsigned short* __restrict__ h3, const int* __restrict__ slotof,
    float* __restrict__ out)
{
    const int n = blockIdx.x * 4 + (threadIdx.x >> 6);
    const int lane = threadIdx.x & 63;
    const int s0 = slotof[n * 2], s1 = slotof[n * 2 + 1];
    const unsigned short* r0 = h3 + (size_t)s0 * DDIM;
    const unsigned short* r1 = h3 + (size_t)s1 * DDIM;
    float* o = out + (size_t)n * DDIM;
#pragma unroll
    for (int j = 0; j < 4; ++j) {
        const int c = j * 256 + lane * 4;
        const ushort4 a = *(const ushort4*)(r0 + c);
        const ushort4 b = *(const ushort4*)(r1 + c);
        float4 v;
        v.x = b2f(a.x) + b2f(b.x);
        v.y = b2f(a.y) + b2f(b.y);
        v.z = b2f(a.z) + b2f(b.z);
        v.w = b2f(a.w) + b2f(b.w);
        *(float4*)(o + c) = v;
    }
}

extern "C" void kernel_launch(void* const* d_in, const int* in_sizes, int n_in,
                              void* d_out, int out_size, void* d_ws, size_t ws_size,
                              hipStream_t stream)
{
    const float* x  = (const float*)d_in[0];
    const float* Wg = (const float*)d_in[1];
    const float* bg = (const float*)d_in[2];
    const float* W1 = (const float*)d_in[3];
    const float* b1 = (const float*)d_in[4];
    const float* W2 = (const float*)d_in[5];
    const float* b2 = (const float*)d_in[6];
    const float* W3 = (const float*)d_in[7];
    const float* b3 = (const float*)d_in[8];
    float* out = (float*)d_out;

    char* ws = (char*)d_ws;
    int*   toff   = (int*)(ws + OFF_TOFF);
    char*  zbuf   = ws + OFF_ZBUF;
    int*   top2e  = (int*)(ws + OFF_T2E);
    float* top2g  = (float*)(ws + OFF_T2G);
    int*   slotof = (int*)(ws + OFF_SLOT);
    int*   tok    = (int*)(ws + OFF_TOK);
    float* gat    = (float*)(ws + OFF_GAT);
    unsigned short* xbu = (unsigned short*)(ws + OFF_XB);
    __bf16* xb  = (__bf16*)(ws + OFF_XB);
    __bf16* w1t = (__bf16*)(ws + OFF_W1T);
    __bf16* w2t = (__bf16*)(ws + OFF_W2T);
    __bf16* w3t = (__bf16*)(ws + OFF_W3T);
    __bf16* h2  = (__bf16*)(ws + OFF_H2);
    __bf16* h3  = (__bf16*)(ws + OFF_H3);

    // fused: gating + x->bf16 conversion || weight transposes (concurrent)
    gate_trans<<<dim3(832, NEXP), 256, 0, stream>>>(
        x, Wg, bg, xbu, top2e, top2g, W1, W2, W3, w1t, w2t, w3t);
    // routing (no atomics, no memsets)
    route<<<1, 1024, 0, stream>>>(top2e, top2g, toff, tok, gat, slotof, (float*)zbuf);

    // expert MLP: fused L1+L2 at BM=32 (R14-verified), then L3 at 128x128
    egemm12<<<NT32, 256, 0, stream>>>(xb, w1t, w2t, b1, b2, toff, tok, zbuf, h2);
    egemm3<HDIM, DDIM><<<dim3(DDIM / 128, NT128), 256, 0, stream>>>(
        h2, w3t, b3, toff, gat, h3);

    // combine the two expert contributions per token (4 tokens/block)
    combine<<<NTOK / 4, 256, 0, stream>>>((const unsigned short*)h3, slotof, out);
}